// Round 1
// baseline (241.989 us; speedup 1.0000x reference)
//
#include <hip/hip_runtime.h>

// Trajectron sliding-window LSTM embed:
//   inputs [T=256, B=128, N=4, D=2] f32
//   his LSTM H=32 over n=3; int LSTM H=8 over n=0; window 64 ending at t
//   out[t,b,:] = [h_his | h_int] @ W_out.T + b_out   -> [256,128,2] f32
//
// Round-13 (fusion): int_kernel (~100us) and his_kernel (104us) were VALU/
// latency-bound at 4 resp. 2 waves/SIMD and ran SERIALLY (only coupling:
// epilogue sum e_his + e_int + b_out). Fuse into ONE dispatch:
//   - prep pre-initializes out with b_out (64 extra blocks, float4 stores)
//   - both roles atomicAdd their contribution (2 atomics/word, no contention)
//   - 6144 blocks, role by bid%3 (0 -> his id bid/3; else int id bid-bid/3-1)
//     so every CU gets a ~1:2 his:int wave mix -> 4 waves/SIMD of mixed work;
//     each role's stalls (MFMA latency, LDS lgkmcnt drain, trans chains) are
//     filled by the other role's issue stream.
// Kernel internals are unchanged from the verified R11/R12 versions.

typedef float v2f __attribute__((ext_vector_type(2)));
typedef float v4f __attribute__((ext_vector_type(4)));
typedef _Float16 h8v __attribute__((ext_vector_type(8)));

static __device__ __forceinline__ float fexp2(float x) {
    return __builtin_amdgcn_exp2f(x);
}
static __device__ __forceinline__ float frcp(float x) {
    return __builtin_amdgcn_rcpf(x);
}
static __device__ __forceinline__ void pk_fma(v2f& d, v2f a, v2f b) {
    asm("v_pk_fma_f32 %0, %1, %2, %0" : "+v"(d) : "v"(a), "v"(b));
}
static __device__ __forceinline__ v2f loh(v4f v) {
    return __builtin_shufflevector(v, v, 0, 1);
}
static __device__ __forceinline__ v2f hih(v4f v) {
    return __builtin_shufflevector(v, v, 2, 3);
}
static __device__ __forceinline__ unsigned short f2h(float f) {
    _Float16 h = (_Float16)f;
    unsigned short u;
    __builtin_memcpy(&u, &h, 2);
    return u;
}

#define LOG2E    1.442695041f
#define TWOLOG2E 2.885390082f

// ws layout:
//   [0,256) hisX  [256,384) hisB  [384,4480) hisW      (legacy, unused)
//   [4480,4544) intX [4544,4576) intB [4576,4832) intW (int role)
//   [5120,5248) hisBP : fp32 permuted-prescaled bias, index p
//   [5376,5632) hisXP : fp32 permuted-prescaled Wih, 2p+{0,1}
//   ushort idx [11776, 15872): hisWH fp16 permuted-prescaled Whh [128][32]
// permutation p = T*16+n -> orig row r = (T>>1)*32 + 2n + (T&1)
// scale s_r = -log2e (i,f,o rows) / -2log2e (g rows)
__global__ __launch_bounds__(256) void prep_kernel(
    const float* __restrict__ Wih_his, const float* __restrict__ Whh_his,
    const float* __restrict__ bih_his, const float* __restrict__ bhh_his,
    const float* __restrict__ Wih_int, const float* __restrict__ Whh_int,
    const float* __restrict__ bih_int, const float* __restrict__ bhh_int,
    float* __restrict__ ws, const float* __restrict__ b_out,
    float* __restrict__ out)
{
    const int i = blockIdx.x * 256 + threadIdx.x;
    if (i < 4480) {
        // legacy his regions (harmless) -- keep indices stable
        if (i < 256) {
            const int r = i >> 1;
            const float s = (r >= 64 && r < 96) ? -TWOLOG2E : -LOG2E;
            ws[i] = Wih_his[i] * s;
        } else if (i < 384) {
            const int r = i - 256;
            const float s = (r >= 64 && r < 96) ? -TWOLOG2E : -LOG2E;
            ws[i] = (bih_his[r] + bhh_his[r]) * s;
        } else {
            const int e = i - 384, r = e >> 5;
            const float s = (r >= 64 && r < 96) ? -TWOLOG2E : -LOG2E;
            ws[i] = Whh_his[e] * s;
        }
    } else if (i < 4544) {              // intX
        const int e = i - 4480, r = e >> 1;
        const float s = (r >= 16 && r < 24) ? -TWOLOG2E : -LOG2E;
        ws[i] = Wih_int[e] * s;
    } else if (i < 4576) {              // intB
        const int r = i - 4544;
        const float s = (r >= 16 && r < 24) ? -TWOLOG2E : -LOG2E;
        ws[i] = (bih_int[r] + bhh_int[r]) * s;
    } else if (i < 4832) {              // intW
        const int e = i - 4576, r = e >> 3;
        const float s = (r >= 16 && r < 24) ? -TWOLOG2E : -LOG2E;
        ws[i] = Whh_int[e] * s;
    } else if (i < 4960) {              // hisBP (permuted bias, fp32)
        const int p = i - 4832;
        const int T = p >> 4, n = p & 15;
        const int gi = T >> 1, u = 2 * n + (T & 1);
        const int r = gi * 32 + u;
        const float s = (gi == 2) ? -TWOLOG2E : -LOG2E;
        ws[5120 + p] = (bih_his[r] + bhh_his[r]) * s;
    } else if (i < 5216) {              // hisXP (permuted Wih, fp32)
        const int e = i - 4960;
        const int p = e >> 1, comp = e & 1;
        const int T = p >> 4, n = p & 15;
        const int gi = T >> 1, u = 2 * n + (T & 1);
        const int r = gi * 32 + u;
        const float s = (gi == 2) ? -TWOLOG2E : -LOG2E;
        ws[5376 + e] = Wih_his[r * 2 + comp] * s;
    } else if (i < 9312) {              // hisWH (permuted Whh, fp16)
        const int e = i - 5216;
        const int p = e >> 5, k = e & 31;
        const int T = p >> 4, n = p & 15;
        const int gi = T >> 1, u = 2 * n + (T & 1);
        const int r = gi * 32 + u;
        const float s = (gi == 2) ? -TWOLOG2E : -LOG2E;
        reinterpret_cast<unsigned short*>(ws)[11776 + e] =
            f2h(Whh_his[r * 32 + k] * s);
    } else if (i >= 9472) {             // out init: b_out broadcast
        const int j = i - 9472;         // 0..16383, one float4 each
        float4 v;
        v.x = b_out[0]; v.y = b_out[1];
        v.z = b_out[0]; v.w = b_out[1];
        reinterpret_cast<float4*>(out)[j] = v;
    }
}

// ---------- int LSTM role: 8 chains per wave, unit-per-lane (R11) --------
static __device__ __forceinline__ void int_body(
    const int W, const int lane,
    const float* __restrict__ inp, const float* __restrict__ ws,
    const float* __restrict__ W_out, float* __restrict__ out,
    float ib[2][8][8])
{
    const int t    = W >> 4;
    const int g    = lane >> 3;
    const int u    = lane & 7;
    const int b    = ((W & 15) << 3) | g;
    const int nsteps = (t >= 63) ? 64 : (t + 1);
    const int tau0   = (t >= 63) ? (t - 63) : 0;

    v2f wi[4][4], wxi[4];
    float bi[4];
    {
        const v2f* wsWi = reinterpret_cast<const v2f*>(ws + 4576);
        const v2f* wsXi = reinterpret_cast<const v2f*>(ws + 4480);
#pragma unroll
        for (int q = 0; q < 4; ++q) {
            const v2f* row = wsWi + (q * 8 + u) * 4;
#pragma unroll
            for (int k = 0; k < 4; ++k) wi[q][k] = row[k];
            bi[q]  = ws[4544 + q * 8 + u];
            wxi[q] = wsXi[q * 8 + u];
        }
    }

    ib[0][g][u] = 0.f;
    float cc = 0.f, h = 0.f;

    const float* xc = inp + tau0 * 1024 + b * 8;
    float2 xv2 = *reinterpret_cast<const float2*>(xc);
    xc += 1024;

#pragma unroll 1
    for (int s = 0; s < nsteps; ++s) {
        __builtin_amdgcn_wave_barrier();
        asm volatile("s_waitcnt lgkmcnt(0)" ::: "memory");
        __builtin_amdgcn_wave_barrier();

        const int rb = s & 1, wb = rb ^ 1;
        const v4f* ip = reinterpret_cast<const v4f*>(&ib[rb][g][0]);
        const v4f i0 = ip[0], i1 = ip[1];

        float2 nx = {0.f, 0.f};
        if (s + 1 < nsteps) nx = *reinterpret_cast<const float2*>(xc);
        xc += 1024;
        const v2f xv = {xv2.x, xv2.y};

        float a[4];
#pragma unroll
        for (int q = 0; q < 4; ++q) {
            v2f acc = {bi[q], 0.f};
            pk_fma(acc, wxi[q], xv);
            pk_fma(acc, wi[q][0], loh(i0));
            pk_fma(acc, wi[q][1], hih(i0));
            pk_fma(acc, wi[q][2], loh(i1));
            pk_fma(acc, wi[q][3], hih(i1));
            a[q] = acc.x + acc.y;
        }
        const float si = frcp(1.f + fexp2(a[0]));
        const float sf = frcp(1.f + fexp2(a[1]));
        const float tg = fmaf(2.f, frcp(1.f + fexp2(a[2])), -1.f);
        const float so = frcp(1.f + fexp2(a[3]));
        cc = fmaf(sf, cc, si * tg);
        h = so * fmaf(-2.f, frcp(1.f + fexp2(TWOLOG2E * cc)), 1.f);
        ib[wb][g][u] = h;

        xv2 = nx;
    }

    float e0 = W_out[32 + u] * h;
    float e1 = W_out[72 + u] * h;
#pragma unroll
    for (int m = 4; m >= 1; m >>= 1) {
        e0 += __shfl_xor(e0, m);
        e1 += __shfl_xor(e1, m);
    }
    if (u == 0) {
        const int chain = t * 128 + b;
        atomicAdd(&out[2 * chain],     e0);
        atomicAdd(&out[2 * chain + 1], e1);
    }
}

// ---------- his LSTM role: 16 chains per wave via MFMA (R12) -------------
static __device__ __forceinline__ void his_body(
    const int Wd, const int lane,
    const float* __restrict__ inp, const float* __restrict__ ws,
    const float* __restrict__ W_out, float* __restrict__ out,
    unsigned short hm[2][16][40])
{
    const int n    = lane & 15;
    const int quad = lane >> 4;
    const int t    = Wd >> 3;                  // uniform per wave
    const int bg   = Wd & 7;                   // chains bg*16 .. +15
    const int nsteps = (t >= 63) ? 64 : (t + 1);
    const int tau0   = (t >= 63) ? (t - 63) : 0;

    // B-frags: tile T rows p=T*16+n, k=quad*8..+7 (8 fp16 = 4 VGPRs each)
    h8v Bf[8];
    {
        const h8v* wb = reinterpret_cast<const h8v*>(
            reinterpret_cast<const unsigned short*>(ws) + 11776);
#pragma unroll
        for (int T = 0; T < 8; ++T) Bf[T] = wb[(T * 16 + n) * 4 + quad];
    }
    // C-init constants (x-part): bias, w0, w1 for row p=T*16+n
    float cb[8], cw0[8], cw1[8];
#pragma unroll
    for (int T = 0; T < 8; ++T) {
        const int p = T * 16 + n;
        cb[T]  = ws[5120 + p];
        cw0[T] = ws[5376 + 2 * p];
        cw1[T] = ws[5376 + 2 * p + 1];
    }

    // x for this lane's 4 chains (quad*4+r), n=3 slot
    const int bbase = bg * 16 + quad * 4;
    const float* xp = inp + tau0 * 1024 + bbase * 8 + 6;
    float2 xc[4];
#pragma unroll
    for (int r = 0; r < 4; ++r)
        xc[r] = *reinterpret_cast<const float2*>(xp + r * 8);
    xp += 1024;

    h8v Af = {};              // h = 0
    float cs[4][2] = {};      // cell state [chain-reg][unit-pair]
    float h0[4] = {}, h1[4] = {};

#pragma unroll 1
    for (int s = 0; s < nsteps; ++s) {
        float2 xn[4];
        if (s + 1 < nsteps) {               // wave-uniform branch
#pragma unroll
            for (int r = 0; r < 4; ++r)
                xn[r] = *reinterpret_cast<const float2*>(xp + r * 8);
        } else {
#pragma unroll
            for (int r = 0; r < 4; ++r) xn[r] = make_float2(0.f, 0.f);
        }
        xp += 1024;

        // 8 MFMAs: D[T] = H @ WhhP_T + (Wih x + b)
        v4f D[8];
#pragma unroll
        for (int T = 0; T < 8; ++T) {
            v4f C;
#pragma unroll
            for (int r = 0; r < 4; ++r)
                C[r] = fmaf(cw1[T], xc[r].y, fmaf(cw0[T], xc[r].x, cb[T]));
            D[T] = __builtin_amdgcn_mfma_f32_16x16x32_f16(Af, Bf[T], C, 0, 0, 0);
        }

        // lane-local activations: 4 chains x units {2n, 2n+1}
        // tiles: 0,1=i  2,3=f  4,5=g  6,7=o  (even tile -> unit 2n)
#pragma unroll
        for (int r = 0; r < 4; ++r) {
            {
                const float si = frcp(1.f + fexp2(D[0][r]));
                const float sf = frcp(1.f + fexp2(D[2][r]));
                const float tg = fmaf(2.f, frcp(1.f + fexp2(D[4][r])), -1.f);
                const float so = frcp(1.f + fexp2(D[6][r]));
                const float cn = fmaf(sf, cs[r][0], si * tg);
                cs[r][0] = cn;
                h0[r] = so * fmaf(-2.f, frcp(1.f + fexp2(TWOLOG2E * cn)), 1.f);
            }
            {
                const float si = frcp(1.f + fexp2(D[1][r]));
                const float sf = frcp(1.f + fexp2(D[3][r]));
                const float tg = fmaf(2.f, frcp(1.f + fexp2(D[5][r])), -1.f);
                const float so = frcp(1.f + fexp2(D[7][r]));
                const float cn = fmaf(sf, cs[r][1], si * tg);
                cs[r][1] = cn;
                h1[r] = so * fmaf(-2.f, frcp(1.f + fexp2(TWOLOG2E * cn)), 1.f);
            }
        }

        // transpose h back to A-layout via wave-private LDS (skip last step)
        if (s + 1 < nsteps) {
            const int bf = s & 1;
#pragma unroll
            for (int r = 0; r < 4; ++r) {
                const unsigned pk =
                    ((unsigned)f2h(h1[r]) << 16) | f2h(h0[r]);
                *reinterpret_cast<unsigned*>(&hm[bf][quad * 4 + r][2 * n]) = pk;
            }
            __builtin_amdgcn_wave_barrier();
            asm volatile("s_waitcnt lgkmcnt(0)" ::: "memory");
            __builtin_amdgcn_wave_barrier();
            Af = *reinterpret_cast<const h8v*>(&hm[bf][n][quad * 8]);
        }

#pragma unroll
        for (int r = 0; r < 4; ++r) xc[r] = xn[r];
    }

    // ---- projection: lane has units {2n,2n+1} of 4 chains; reduce over n --
    const float wo0a = W_out[2 * n],      wo0b = W_out[2 * n + 1];
    const float wo1a = W_out[40 + 2 * n], wo1b = W_out[40 + 2 * n + 1];
    float e0[4], e1[4];
#pragma unroll
    for (int r = 0; r < 4; ++r) {
        e0[r] = fmaf(wo0b, h1[r], wo0a * h0[r]);
        e1[r] = fmaf(wo1b, h1[r], wo1a * h0[r]);
#pragma unroll
        for (int m = 1; m <= 8; m <<= 1) {
            e0[r] += __shfl_xor(e0[r], m);
            e1[r] += __shfl_xor(e1[r], m);
        }
    }
    if (n == 0) {
#pragma unroll
        for (int r = 0; r < 4; ++r) {
            const int chain = t * 128 + bbase + r;
            atomicAdd(&out[2 * chain],     e0[r]);
            atomicAdd(&out[2 * chain + 1], e1[r]);
        }
    }
}

// ---------- fused dispatch: 6144 blocks, role by bid%3 -------------------
__global__ __launch_bounds__(64) void lstm_fused(
    const float* __restrict__ inp, const float* __restrict__ ws,
    const float* __restrict__ W_out, float* __restrict__ out)
{
    __shared__ __align__(16) unsigned short hm[2][16][40];  // his role
    __shared__ __align__(16) float ib[2][8][8];             // int role

    const int bid  = blockIdx.x;
    const int lane = threadIdx.x;
    const int d3   = bid / 3;
    if (bid - 3 * d3 == 0) {
        his_body(d3, lane, inp, ws, W_out, out, hm);        // 2048 waves
    } else {
        int_body(bid - d3 - 1, lane, inp, ws, W_out, out, ib); // 4096 waves
    }
}

extern "C" void kernel_launch(void* const* d_in, const int* in_sizes, int n_in,
                              void* d_out, int out_size, void* d_ws, size_t ws_size,
                              hipStream_t stream) {
    const float* inp     = (const float*)d_in[0];
    const float* Wih_his = (const float*)d_in[1];
    const float* Whh_his = (const float*)d_in[2];
    const float* bih_his = (const float*)d_in[3];
    const float* bhh_his = (const float*)d_in[4];
    const float* Wih_int = (const float*)d_in[5];
    const float* Whh_int = (const float*)d_in[6];
    const float* bih_int = (const float*)d_in[7];
    const float* bhh_int = (const float*)d_in[8];
    const float* W_out   = (const float*)d_in[9];
    const float* b_out   = (const float*)d_in[10];
    float* out  = (float*)d_out;
    float* ws   = (float*)d_ws;

    // pre-pass: prescale + permute weights; blocks 37..100 init out = b_out
    prep_kernel<<<dim3(101), dim3(256), 0, stream>>>(
        Wih_his, Whh_his, bih_his, bhh_his,
        Wih_int, Whh_int, bih_int, bhh_int, ws, b_out, out);

    // fused int+his LSTM: 6144 waves of mixed role, atomicAdd epilogues
    lstm_fused<<<dim3(6144), dim3(64), 0, stream>>>(inp, ws, W_out, out);
}

// Round 3
// 197.882 us; speedup vs baseline: 1.2229x; 1.2229x over previous
//
#include <hip/hip_runtime.h>

// Trajectron sliding-window LSTM embed:
//   inputs [T=256, B=128, N=4, D=2] f32
//   his LSTM H=32 over n=3; int LSTM H=8 over n=0; window 64 ending at t
//   out[t,b,:] = [h_his | h_int] @ W_out.T + b_out   -> [256,128,2] f32
//
// Round-15: R14's no-LDS MFMA int kernel was LAYOUT-correct (absmax ~2.7e-3
// = fp16 quantization scale, not a structural error) but fp16 h + fp16 Whh
// cost too much precision (threshold 2.75e-3, data-dependent fails).
// Fix at ZERO MFMA cost via hi/lo split over the idle K-range (int uses only
// K=0..7 of K=32):
//   k 0..7  : W_hi . h_hi     (quad0: A=W_hi row, B=h_hi)
//   k 8..15 : W_hi . h_lo     (quad1: A=W_hi row, B=h_lo)
//   k 16..23: W_lo . h_hi     (quad2: A=W_lo row, B=h_hi)
//   k 24..31: W_lo . h_lo     (quad3: A=W_lo row, B=h_lo)
// with lo = x - fp16(x): fp32-accumulated total = W.h exact to ~2^-21.
// Still 2 MFMAs/step; B-gather is 8 shfl + 4 cndmask (was 4 shfl + mask).
// Also: depth-2 x prefetch (hides L2/HBM latency under 2 full steps).
// his_kernel: verbatim R0/R12 (verified, 104us). prep: legacy regions
// dropped; intWH hi at ushort 16128, lo at ushort 8704 (freed legacy space).

typedef float v2f __attribute__((ext_vector_type(2)));
typedef float v4f __attribute__((ext_vector_type(4)));
typedef _Float16 h8v __attribute__((ext_vector_type(8)));

static __device__ __forceinline__ float fexp2(float x) {
    return __builtin_amdgcn_exp2f(x);
}
static __device__ __forceinline__ float frcp(float x) {
    return __builtin_amdgcn_rcpf(x);
}
static __device__ __forceinline__ unsigned short f2h(float f) {
    _Float16 h = (_Float16)f;
    unsigned short u;
    __builtin_memcpy(&u, &h, 2);
    return u;
}
static __device__ __forceinline__ float h2f(unsigned short u) {
    _Float16 h;
    __builtin_memcpy(&h, &u, 2);
    return (float)h;
}

#define LOG2E    1.442695041f
#define TWOLOG2E 2.885390082f

// ws layout (float index unless noted):
//   ushort [8704,8960)  : intWH_lo fp16 permuted residual Whh_int [32][8]
//       (= float [4352,4480), inside dropped legacy region)
//   [5120,5248) hisBP : fp32 permuted-prescaled bias, index p
//   [5376,5632) hisXP : fp32 permuted-prescaled Wih, 2p+{0,1}
//   ushort [11776,15872): hisWH fp16 permuted-prescaled Whh [128][32]
//       (= float [5888,7936))
//   [7936,7968) intBP : fp32 permuted-prescaled int bias, slot s
//   [7968,8032) intXP : fp32 permuted-prescaled int Wih, 2s+{0,1}
//   ushort [16128,16384): intWH_hi fp16 permuted-prescaled Whh_int [32][8]
//       (= float [8064,8192))
//   [8192,73728) eInt : per-chain int contribution float2[32768]
// his perm p = T*16+n -> orig row r = (T>>1)*32 + 2n + (T&1)
// int perm slot s = T*16+m (m=q*4+r): gate=(4T+(m&3))>>1,
//   unit=2*(m>>2)+(m&1), orig = gate*8+unit
// scale = -log2e (i,f,o rows) / -2log2e (g rows)
__global__ __launch_bounds__(256) void prep_kernel(
    const float* __restrict__ Wih_his, const float* __restrict__ Whh_his,
    const float* __restrict__ bih_his, const float* __restrict__ bhh_his,
    const float* __restrict__ Wih_int, const float* __restrict__ Whh_int,
    const float* __restrict__ bih_int, const float* __restrict__ bhh_int,
    float* __restrict__ ws)
{
    const int i = blockIdx.x * 256 + threadIdx.x;
    if (i < 4832) {
        // legacy regions dropped (nothing reads them)
    } else if (i < 4960) {              // hisBP (permuted bias, fp32)
        const int p = i - 4832;
        const int T = p >> 4, n = p & 15;
        const int gi = T >> 1, u = 2 * n + (T & 1);
        const int r = gi * 32 + u;
        const float s = (gi == 2) ? -TWOLOG2E : -LOG2E;
        ws[5120 + p] = (bih_his[r] + bhh_his[r]) * s;
    } else if (i < 5216) {              // hisXP (permuted Wih, fp32)
        const int e = i - 4960;
        const int p = e >> 1, comp = e & 1;
        const int T = p >> 4, n = p & 15;
        const int gi = T >> 1, u = 2 * n + (T & 1);
        const int r = gi * 32 + u;
        const float s = (gi == 2) ? -TWOLOG2E : -LOG2E;
        ws[5376 + e] = Wih_his[r * 2 + comp] * s;
    } else if (i < 9312) {              // hisWH (permuted Whh, fp16)
        const int e = i - 5216;
        const int p = e >> 5, k = e & 31;
        const int T = p >> 4, n = p & 15;
        const int gi = T >> 1, u = 2 * n + (T & 1);
        const int r = gi * 32 + u;
        const float s = (gi == 2) ? -TWOLOG2E : -LOG2E;
        reinterpret_cast<unsigned short*>(ws)[11776 + e] =
            f2h(Whh_his[r * 32 + k] * s);
    } else if (i < 9344) {              // intBP (permuted int bias, fp32)
        const int s = i - 9312;
        const int T = s >> 4, m = s & 15, r = m & 3;
        const int gate = (4 * T + r) >> 1, unit = 2 * (m >> 2) + (r & 1);
        const int orig = gate * 8 + unit;
        const float sc = (gate == 2) ? -TWOLOG2E : -LOG2E;
        ws[7936 + s] = (bih_int[orig] + bhh_int[orig]) * sc;
    } else if (i < 9408) {              // intXP (permuted int Wih, fp32)
        const int e = i - 9344;
        const int s = e >> 1, comp = e & 1;
        const int T = s >> 4, m = s & 15, r = m & 3;
        const int gate = (4 * T + r) >> 1, unit = 2 * (m >> 2) + (r & 1);
        const int orig = gate * 8 + unit;
        const float sc = (gate == 2) ? -TWOLOG2E : -LOG2E;
        ws[7968 + e] = Wih_int[orig * 2 + comp] * sc;
    } else if (i < 9664) {              // intWH hi+lo (permuted, fp16 [32][8])
        const int e = i - 9408;
        const int s = e >> 3, k = e & 7;
        const int T = s >> 4, m = s & 15, r = m & 3;
        const int gate = (4 * T + r) >> 1, unit = 2 * (m >> 2) + (r & 1);
        const int orig = gate * 8 + unit;
        const float sc = (gate == 2) ? -TWOLOG2E : -LOG2E;
        const float w = Whh_int[orig * 8 + k] * sc;
        const unsigned short hi = f2h(w);
        const unsigned short lo = f2h(w - h2f(hi));
        reinterpret_cast<unsigned short*>(ws)[16128 + e] = hi;
        reinterpret_cast<unsigned short*>(ws)[8704 + e]  = lo;
    }
}

// ---------- int LSTM: 16 chains per wave via MFMA, no LDS, hi/lo exact ---
//   D[T] (16 gate-slots x 16 chains) = WhhP_T(A) . h(B) + xpart(C)
//   A-frag: lane(q,n) holds A[m=n][k=q*8+j]:
//     q0,q1 -> W_hi row; q2,q3 -> W_lo row
//   B-frag: lane(q,n) holds B[k=q*8+j][col=n]:
//     q0,q2 -> h_hi units; q1,q3 -> h_lo units
//   D:      lane(q,n) holds rows q*4+r, col n -> gates of units {2q,2q+1}
__global__ __launch_bounds__(64) void intm_kernel(
    const float* __restrict__ inp, const float* __restrict__ ws,
    const float* __restrict__ W_out, float* __restrict__ eInt)
{
    const int lane = threadIdx.x;
    const int n    = lane & 15;
    const int q    = lane >> 4;
    const int Wd   = blockIdx.x;               // 0..2047
    const int t    = Wd >> 3;                  // uniform per wave
    const int bg   = Wd & 7;                   // chains bg*16 .. +15
    const int nsteps = (t >= 63) ? 64 : (t + 1);
    const int tau0   = (t >= 63) ? (t - 63) : 0;

    // A-frags: hi rows for quads 0,1; lo rows for quads 2,3
    h8v Ai[2];
    {
        const h8v* wah = reinterpret_cast<const h8v*>(
            reinterpret_cast<const unsigned short*>(ws) + 16128);
        const h8v* wal = reinterpret_cast<const h8v*>(
            reinterpret_cast<const unsigned short*>(ws) + 8704);
#pragma unroll
        for (int T = 0; T < 2; ++T) {
            const h8v vh = wah[T * 16 + n];
            const h8v vl = wal[T * 16 + n];
            Ai[T] = (q < 2) ? vh : vl;
        }
    }

    // C-init constants for this lane's 8 gate-slots (slot = T*16 + q*4 + r)
    float cb[2][4], cw0v[2][4], cw1v[2][4];
#pragma unroll
    for (int T = 0; T < 2; ++T)
#pragma unroll
        for (int r = 0; r < 4; ++r) {
            const int s = T * 16 + q * 4 + r;
            cb[T][r]   = ws[7936 + s];
            cw0v[T][r] = ws[7968 + 2 * s];
            cw1v[T][r] = ws[7968 + 2 * s + 1];
        }

    // x for chain n (slot n=0 of inputs); depth-2 prefetch
    const int chain = bg * 16 + n;
    const float* xp = inp + tau0 * 1024 + chain * 8;
    float2 xv = *reinterpret_cast<const float2*>(xp);
    float2 x1 = make_float2(0.f, 0.f);
    if (nsteps > 1) x1 = *reinterpret_cast<const float2*>(xp + 1024);
    xp += 2048;

    union BU { unsigned u[4]; h8v h; } bf;
    bf.u[0] = bf.u[1] = bf.u[2] = bf.u[3] = 0;   // h = 0

    float cI0 = 0.f, cI1 = 0.f, h0 = 0.f, h1 = 0.f;

#pragma unroll 1
    for (int s = 0; s < nsteps; ++s) {
        float2 x2 = make_float2(0.f, 0.f);
        if (s + 2 < nsteps)                     // wave-uniform branch
            x2 = *reinterpret_cast<const float2*>(xp);
        xp += 1024;

        // C-init (x-part) + 2 MFMAs
        v4f C0, C1;
#pragma unroll
        for (int r = 0; r < 4; ++r) {
            C0[r] = fmaf(cw1v[0][r], xv.y, fmaf(cw0v[0][r], xv.x, cb[0][r]));
            C1[r] = fmaf(cw1v[1][r], xv.y, fmaf(cw0v[1][r], xv.x, cb[1][r]));
        }
        const v4f D0 = __builtin_amdgcn_mfma_f32_16x16x32_f16(Ai[0], bf.h, C0, 0, 0, 0);
        const v4f D1 = __builtin_amdgcn_mfma_f32_16x16x32_f16(Ai[1], bf.h, C1, 0, 0, 0);

        // lane-local activations: units {2q, 2q+1} of chain n
        // slot decode: T=0: r=0,1 -> i(u0,u1); r=2,3 -> f(u0,u1)
        //              T=1: r=0,1 -> g(u0,u1); r=2,3 -> o(u0,u1)
        {
            const float si = frcp(1.f + fexp2(D0[0]));
            const float sf = frcp(1.f + fexp2(D0[2]));
            const float tg = fmaf(2.f, frcp(1.f + fexp2(D1[0])), -1.f);
            const float so = frcp(1.f + fexp2(D1[2]));
            const float cn = fmaf(sf, cI0, si * tg);
            cI0 = cn;
            h0 = so * fmaf(-2.f, frcp(1.f + fexp2(TWOLOG2E * cn)), 1.f);
        }
        {
            const float si = frcp(1.f + fexp2(D0[1]));
            const float sf = frcp(1.f + fexp2(D0[3]));
            const float tg = fmaf(2.f, frcp(1.f + fexp2(D1[1])), -1.f);
            const float so = frcp(1.f + fexp2(D1[3]));
            const float cn = fmaf(sf, cI1, si * tg);
            cI1 = cn;
            h1 = so * fmaf(-2.f, frcp(1.f + fexp2(TWOLOG2E * cn)), 1.f);
        }

        // h -> B-frag: hi pair + lo (residual) pair, gather dword d from
        // lane d*16+n; quads 0,2 take hi, quads 1,3 take lo
        if (s + 1 < nsteps) {
            const unsigned short h0h = f2h(h0), h1h = f2h(h1);
            const float h0l = h0 - h2f(h0h);
            const float h1l = h1 - h2f(h1h);
            const unsigned pkh = ((unsigned)h1h << 16) | h0h;
            const unsigned pkl = ((unsigned)f2h(h1l) << 16) | f2h(h0l);
#pragma unroll
            for (int d = 0; d < 4; ++d) {
                const unsigned uh = (unsigned)__shfl((int)pkh, d * 16 + n);
                const unsigned ul = (unsigned)__shfl((int)pkl, d * 16 + n);
                bf.u[d] = (q & 1) ? ul : uh;
            }
        }

        xv = x1;
        x1 = x2;
    }

    // projection: lane(q,n) has units {2q,2q+1} of chain n; reduce over q
    const float wo0a = W_out[32 + 2 * q], wo0b = W_out[33 + 2 * q];
    const float wo1a = W_out[72 + 2 * q], wo1b = W_out[73 + 2 * q];
    float e0 = fmaf(wo0b, h1, wo0a * h0);
    float e1 = fmaf(wo1b, h1, wo1a * h0);
    e0 += __shfl_xor(e0, 16); e1 += __shfl_xor(e1, 16);
    e0 += __shfl_xor(e0, 32); e1 += __shfl_xor(e1, 32);
    if (lane < 16) {
        float2 o; o.x = e0; o.y = e1;
        reinterpret_cast<float2*>(eInt)[t * 128 + chain] = o;
    }
}

// ---------- his LSTM: 16 chains per wave via MFMA (R12, verified) --------
__global__ __launch_bounds__(64) void his_kernel(
    const float* __restrict__ inp, const float* __restrict__ ws,
    const float* __restrict__ W_out, const float* __restrict__ b_out,
    const float* __restrict__ eInt, float* __restrict__ out)
{
    __shared__ __align__(16) unsigned short hm[2][16][40];  // fp16 h, padded

    const int lane = threadIdx.x;
    const int n    = lane & 15;
    const int quad = lane >> 4;
    const int Wd   = blockIdx.x;               // 0..2047
    const int t    = Wd >> 3;                  // uniform per wave
    const int bg   = Wd & 7;                   // chains bg*16 .. +15
    const int nsteps = (t >= 63) ? 64 : (t + 1);
    const int tau0   = (t >= 63) ? (t - 63) : 0;

    // B-frags: tile T rows p=T*16+n, k=quad*8..+7 (8 fp16 = 4 VGPRs each)
    h8v Bf[8];
    {
        const h8v* wb = reinterpret_cast<const h8v*>(
            reinterpret_cast<const unsigned short*>(ws) + 11776);
#pragma unroll
        for (int T = 0; T < 8; ++T) Bf[T] = wb[(T * 16 + n) * 4 + quad];
    }
    // C-init constants (x-part): bias, w0, w1 for row p=T*16+n
    float cb[8], cw0[8], cw1[8];
#pragma unroll
    for (int T = 0; T < 8; ++T) {
        const int p = T * 16 + n;
        cb[T]  = ws[5120 + p];
        cw0[T] = ws[5376 + 2 * p];
        cw1[T] = ws[5376 + 2 * p + 1];
    }

    // x for this lane's 4 chains (quad*4+r), n=3 slot
    const int bbase = bg * 16 + quad * 4;
    const float* xp = inp + tau0 * 1024 + bbase * 8 + 6;
    float2 xc[4];
#pragma unroll
    for (int r = 0; r < 4; ++r)
        xc[r] = *reinterpret_cast<const float2*>(xp + r * 8);
    xp += 1024;

    h8v Af = {};              // h = 0
    float cs[4][2] = {};      // cell state [chain-reg][unit-pair]
    float h0[4] = {}, h1[4] = {};

#pragma unroll 1
    for (int s = 0; s < nsteps; ++s) {
        float2 xn[4];
        if (s + 1 < nsteps) {               // wave-uniform branch
#pragma unroll
            for (int r = 0; r < 4; ++r)
                xn[r] = *reinterpret_cast<const float2*>(xp + r * 8);
        } else {
#pragma unroll
            for (int r = 0; r < 4; ++r) xn[r] = make_float2(0.f, 0.f);
        }
        xp += 1024;

        // 8 MFMAs: D[T] = H @ WhhP_T + (Wih x + b)
        v4f D[8];
#pragma unroll
        for (int T = 0; T < 8; ++T) {
            v4f C;
#pragma unroll
            for (int r = 0; r < 4; ++r)
                C[r] = fmaf(cw1[T], xc[r].y, fmaf(cw0[T], xc[r].x, cb[T]));
            D[T] = __builtin_amdgcn_mfma_f32_16x16x32_f16(Af, Bf[T], C, 0, 0, 0);
        }

        // lane-local activations: 4 chains x units {2n, 2n+1}
        // tiles: 0,1=i  2,3=f  4,5=g  6,7=o  (even tile -> unit 2n)
#pragma unroll
        for (int r = 0; r < 4; ++r) {
            {
                const float si = frcp(1.f + fexp2(D[0][r]));
                const float sf = frcp(1.f + fexp2(D[2][r]));
                const float tg = fmaf(2.f, frcp(1.f + fexp2(D[4][r])), -1.f);
                const float so = frcp(1.f + fexp2(D[6][r]));
                const float cn = fmaf(sf, cs[r][0], si * tg);
                cs[r][0] = cn;
                h0[r] = so * fmaf(-2.f, frcp(1.f + fexp2(TWOLOG2E * cn)), 1.f);
            }
            {
                const float si = frcp(1.f + fexp2(D[1][r]));
                const float sf = frcp(1.f + fexp2(D[3][r]));
                const float tg = fmaf(2.f, frcp(1.f + fexp2(D[5][r])), -1.f);
                const float so = frcp(1.f + fexp2(D[7][r]));
                const float cn = fmaf(sf, cs[r][1], si * tg);
                cs[r][1] = cn;
                h1[r] = so * fmaf(-2.f, frcp(1.f + fexp2(TWOLOG2E * cn)), 1.f);
            }
        }

        // transpose h back to A-layout via wave-private LDS (skip last step)
        if (s + 1 < nsteps) {
            const int bf = s & 1;
#pragma unroll
            for (int r = 0; r < 4; ++r) {
                const unsigned pk =
                    ((unsigned)f2h(h1[r]) << 16) | f2h(h0[r]);
                *reinterpret_cast<unsigned*>(&hm[bf][quad * 4 + r][2 * n]) = pk;
            }
            __builtin_amdgcn_wave_barrier();
            asm volatile("s_waitcnt lgkmcnt(0)" ::: "memory");
            __builtin_amdgcn_wave_barrier();
            Af = *reinterpret_cast<const h8v*>(&hm[bf][n][quad * 8]);
        }

#pragma unroll
        for (int r = 0; r < 4; ++r) xc[r] = xn[r];
    }

    // ---- projection: lane has units {2n,2n+1} of 4 chains; reduce over n --
    const float wo0a = W_out[2 * n],      wo0b = W_out[2 * n + 1];
    const float wo1a = W_out[40 + 2 * n], wo1b = W_out[40 + 2 * n + 1];
    float e0[4], e1[4];
#pragma unroll
    for (int r = 0; r < 4; ++r) {
        e0[r] = fmaf(wo0b, h1[r], wo0a * h0[r]);
        e1[r] = fmaf(wo1b, h1[r], wo1a * h0[r]);
#pragma unroll
        for (int m = 1; m <= 8; m <<= 1) {
            e0[r] += __shfl_xor(e0[r], m);
            e1[r] += __shfl_xor(e1[r], m);
        }
    }
    if (n == 0) {
        const float bo0 = b_out[0], bo1 = b_out[1];
#pragma unroll
        for (int r = 0; r < 4; ++r) {
            const int chain = t * 128 + bbase + r;
            const float2 ei = reinterpret_cast<const float2*>(eInt)[chain];
            float2 o;
            o.x = e0[r] + ei.x + bo0;
            o.y = e1[r] + ei.y + bo1;
            reinterpret_cast<float2*>(out)[chain] = o;
        }
    }
}

extern "C" void kernel_launch(void* const* d_in, const int* in_sizes, int n_in,
                              void* d_out, int out_size, void* d_ws, size_t ws_size,
                              hipStream_t stream) {
    const float* inp     = (const float*)d_in[0];
    const float* Wih_his = (const float*)d_in[1];
    const float* Whh_his = (const float*)d_in[2];
    const float* bih_his = (const float*)d_in[3];
    const float* bhh_his = (const float*)d_in[4];
    const float* Wih_int = (const float*)d_in[5];
    const float* Whh_int = (const float*)d_in[6];
    const float* bih_int = (const float*)d_in[7];
    const float* bhh_int = (const float*)d_in[8];
    const float* W_out   = (const float*)d_in[9];
    const float* b_out   = (const float*)d_in[10];
    float* out  = (float*)d_out;
    float* ws   = (float*)d_ws;
    float* eInt = ws + 8192;

    // pre-pass: prescale + permute weights (his fp16 Whh + int hi/lo Whh)
    prep_kernel<<<dim3(38), dim3(256), 0, stream>>>(
        Wih_his, Whh_his, bih_his, bhh_his,
        Wih_int, Whh_int, bih_int, bhh_int, ws);

    // int LSTM: 2048 waves, 16 chains each, 2 MFMAs per step, no LDS
    intm_kernel<<<dim3(2048), dim3(64), 0, stream>>>(inp, ws, W_out, eInt);

    // his LSTM: 2048 waves, 16 chains each, 8 MFMAs per step
    his_kernel<<<dim3(2048), dim3(64), 0, stream>>>(
        inp, ws, W_out, b_out, eInt, out);
}